// Round 17
// baseline (405.316 us; speedup 1.0000x reference)
//
#include <hip/hip_runtime.h>
#include <math.h>

#define HID 128
#define EDGE_D 32
#define SC 0.36067376f  // 0.25 * log2(e)
#define AS1 __attribute__((address_space(1)))
#define AS3 __attribute__((address_space(3)))
#define RL __builtin_amdgcn_readlane

typedef unsigned short u16;
typedef unsigned int u32;
typedef __bf16 bf16x8 __attribute__((ext_vector_type(8)));
typedef float f32x4 __attribute__((ext_vector_type(4)));
typedef u32 u32x4 __attribute__((ext_vector_type(4)));
typedef u32 u32x2 __attribute__((ext_vector_type(2)));

static __device__ __forceinline__ u16 f2bf(float f) {
  u32 u = __float_as_uint(f);
  u += 0x7fffu + ((u >> 16) & 1u);
  return (u16)(u >> 16);
}
static __device__ __forceinline__ u32 pack2(float a, float b) {
  return (u32)f2bf(a) | ((u32)f2bf(b) << 16);
}
static __device__ __forceinline__ float bflo(u32 w) { return __uint_as_float(w << 16); }
static __device__ __forceinline__ float bfhi(u32 w) { return __uint_as_float(w & 0xffff0000u); }
static __device__ __forceinline__ float bf2f16(u16 b) {
  return __uint_as_float(((u32)b) << 16);
}
// all-lanes sum within each 16-lane row via DPP row rotates (pure VALU)
static __device__ __forceinline__ float grp16_sum(float x) {
  x += __int_as_float(__builtin_amdgcn_mov_dpp(__float_as_int(x), 0x128, 0xf, 0xf, true));
  x += __int_as_float(__builtin_amdgcn_mov_dpp(__float_as_int(x), 0x124, 0xf, 0xf, true));
  x += __int_as_float(__builtin_amdgcn_mov_dpp(__float_as_int(x), 0x122, 0xf, 0xf, true));
  x += __int_as_float(__builtin_amdgcn_mov_dpp(__float_as_int(x), 0x121, 0xf, 0xf, true));
  return x;
}
static __device__ __forceinline__ float wave_allreduce_sum(float v) {
#pragma unroll
  for (int off = 32; off > 0; off >>= 1) v += __shfl_xor(v, off);
  return v;
}

// ---------- prelude: weight conversion + Wfold/bfold (blocks 0..1024),
//            LN1 (blocks 1025..2048), dst histogram (blocks 2049..3072) ----------
__global__ __launch_bounds__(256) void prelude_kernel(
    const float* __restrict__ Wq, const float* __restrict__ Wk,
    const float* __restrict__ Wv, const float* __restrict__ Ws,
    const float* __restrict__ W1, const float* __restrict__ W2,
    const float* __restrict__ We, const float* __restrict__ bq,
    u16* __restrict__ WqkvsT, u16* __restrict__ W1T, u16* __restrict__ W2T,
    u16* __restrict__ WbdT, u16* __restrict__ WfoldT, float* __restrict__ bfold,
    const float* __restrict__ x, u16* __restrict__ hout,
    const float* __restrict__ ln1w, const float* __restrict__ ln1b, int Nn,
    const int* __restrict__ dstp, int* __restrict__ cnt, int E) {
  int bid = blockIdx.x;
  if (bid < 1025) {
    int idx = bid * 256 + threadIdx.x;
    if (idx < 65536) {
      int m = idx >> 7, k = idx & 127;
      const float* Wm = m < 128 ? Wq : m < 256 ? Wk : m < 384 ? Wv : Ws;
      WqkvsT[idx] = f2bf(Wm[k * 128 + (m & 127)]);
    } else if (idx < 131072) {
      int j = idx - 65536;
      int m = j >> 7, k = j & 127;
      W1T[j] = f2bf(W1[k * 512 + m]);
    } else if (idx < 196608) {
      int j = idx - 131072;
      int m = j >> 9, k = j & 511;
      W2T[j] = f2bf(W2[k * 128 + m]);
    } else if (idx < 229376) {
      int j = idx - 196608;  // WbdT [128][256]
      int m = j >> 8, c = j & 255;
      WbdT[j] = ((c >> 5) == (m >> 4)) ? f2bf(We[(c & 31) * 128 + m]) : (u16)0;
    } else if (idx < 262144) {
      int j = idx - 229376;  // WfoldT [256][128]
      int m = j >> 7, k = j & 127;
      int base = (m >> 5) * 16;
      const float* wq = Wq + k * 128 + base;
      const float* we = We + (m & 31) * 128 + base;
      float s = 0.f;
#pragma unroll
      for (int t = 0; t < 16; t++) s = fmaf(wq[t], we[t], s);
      WfoldT[j] = f2bf(s * SC);
    } else if (idx < 262400) {
      int m = idx - 262144;  // bfold [256]
      int base = (m >> 5) * 16;
      const float* we = We + (m & 31) * 128 + base;
      float s = 0.f;
#pragma unroll
      for (int t = 0; t < 16; t++) s = fmaf(bq[base + t], we[t], s);
      bfold[m] = s * SC;
    }
  } else if (bid < 2049) {  // LN1, grid-stride over 1024 blocks
    int b = bid - 1025;
    int lane = threadIdx.x & 63;
    int row0 = b * 4 + (threadIdx.x >> 6);
    for (int row = row0; row < Nn; row += 4096) {
      const float* p = x + (size_t)row * HID;
      float a = p[lane], c = p[lane + 64];
      float s = wave_allreduce_sum(a + c);
      float s2 = wave_allreduce_sum(a * a + c * c);
      float mean = s * (1.f / 128.f);
      float var = s2 * (1.f / 128.f) - mean * mean;
      float rs = rsqrtf(var + 1e-5f);
      u16* o = hout + (size_t)row * HID;
      o[lane] = f2bf((a - mean) * rs * ln1w[lane] + ln1b[lane]);
      o[lane + 64] = f2bf((c - mean) * rs * ln1w[lane + 64] + ln1b[lane + 64]);
    }
  } else {  // histogram, grid-stride over 1024 blocks
    int b = bid - 2049;
    for (int i = b * 256 + threadIdx.x; i < E; i += 262144)
      atomicAdd(&cnt[dstp[i]], 1);
  }
}

// ---------- bf16 MFMA GEMM: tile 128x128, 4 waves, 2-phase double-buffered LDS ----------
#define GSTAGE(buf, kc)                                                        \
  {                                                                            \
    _Pragma("unroll") for (int i = 0; i < 2; i++) {                            \
      int idx = i * 256 + t;                                                   \
      int row = idx >> 2, c4 = idx & 3;                                        \
      __builtin_amdgcn_global_load_lds(                                        \
          (const AS1 u32*)(A + (size_t)(r0 + row) * K + (kc) + c4 * 8),        \
          (AS3 u32*)&As[buf][idx * 8], 16, 0, 0);                              \
      __builtin_amdgcn_global_load_lds(                                        \
          (const AS1 u32*)(Bt + (size_t)(c0 + row) * K + (kc) + c4 * 8),       \
          (AS3 u32*)&Bs[buf][idx * 8], 16, 0, 0);                              \
    }                                                                          \
  }

#define GEMM_CORE                                                              \
  constexpr int NT = K / 32;                                                   \
  GSTAGE(0, 0)                                                                 \
  __syncthreads();                                                             \
  _Pragma("unroll") for (int tt = 0; tt < NT; tt++) {                          \
    if (tt + 1 < NT) GSTAGE((tt + 1) & 1, (tt + 1) * 32)                       \
    bf16x8 a0 = *(const bf16x8*)&As[tt & 1][(w * 32 + sr) * 32 + g * 8];       \
    bf16x8 a1 = *(const bf16x8*)&As[tt & 1][(w * 32 + 16 + sr) * 32 + g * 8];  \
    _Pragma("unroll") for (int nn = 0; nn < 8; nn++) {                         \
      bf16x8 b = *(const bf16x8*)&Bs[tt & 1][(nn * 16 + sr) * 32 + g * 8];     \
      acc[0][nn] = __builtin_amdgcn_mfma_f32_16x16x32_bf16(a0, b, acc[0][nn], 0, 0, 0); \
      acc[1][nn] = __builtin_amdgcn_mfma_f32_16x16x32_bf16(a1, b, acc[1][nn], 0, 0, 0); \
    }                                                                          \
    __syncthreads();                                                           \
  }

// QKV GEMM: y0 -> pq packed ; y1/y2 -> pkv packed ; y3/y4 -> qweb16 (+bfold)
template <int K>
__global__ __launch_bounds__(256) void gemm_qkv(
    const u16* __restrict__ A, const u16* __restrict__ BtQ,
    const u16* __restrict__ BtF, int n,
    const float* __restrict__ bias0, const float* __restrict__ bias1,
    const float* __restrict__ bias2, const float* __restrict__ bfold,
    u32* __restrict__ opq, u32* __restrict__ pkv, u16* __restrict__ qweb16) {
  __shared__ u16 As[2][128 * 32];
  __shared__ u16 Bs[2][128 * 32];
  int t = threadIdx.x;
  int w = t >> 6, lane = t & 63;
  int g = lane >> 4, sr = lane & 15;
  int r0 = blockIdx.x * 128;
  int c0;
  const u16* Bt;
  if (blockIdx.y >= 3) {
    c0 = (blockIdx.y - 3) * 128;
    Bt = BtF;
  } else {
    c0 = blockIdx.y * 128;
    Bt = BtQ;
  }
  f32x4 acc[2][8];
#pragma unroll
  for (int m = 0; m < 2; m++)
#pragma unroll
    for (int nn = 0; nn < 8; nn++) acc[m][nn] = {0.f, 0.f, 0.f, 0.f};

  GEMM_CORE

  if (blockIdx.y == 0) {  // Q packed
#pragma unroll
    for (int m = 0; m < 2; m++)
#pragma unroll
      for (int nn = 0; nn < 4; nn++)
#pragma unroll
        for (int j = 0; j < 4; j++) {
          int row = r0 + w * 32 + m * 16 + g * 4 + j;
          if (row < n) {
            int cj = nn * 16 + sr;
            opq[((size_t)row << 6) + cj] =
                pack2(acc[m][nn][j] + bias0[cj], acc[m][nn + 4][j] + bias0[cj + 64]);
          }
        }
    return;
  }
  if (blockIdx.y < 3) {  // K/V packed
    const float* bp = blockIdx.y == 1 ? bias1 : bias2;
    int which = blockIdx.y - 1;
#pragma unroll
    for (int m = 0; m < 2; m++)
#pragma unroll
      for (int nn = 0; nn < 4; nn++)
#pragma unroll
        for (int j = 0; j < 4; j++) {
          int row = r0 + w * 32 + m * 16 + g * 4 + j;
          if (row < n) {
            int cj = nn * 16 + sr;
            pkv[((size_t)row << 7) + (cj << 1) + which] =
                pack2(acc[m][nn][j] + bp[cj], acc[m][nn + 4][j] + bp[cj + 64]);
          }
        }
    return;
  }
  // y3/y4: qwe panels -> u16 [node][256]
  const float* bf = bfold + c0;
#pragma unroll
  for (int m = 0; m < 2; m++)
#pragma unroll
    for (int nn = 0; nn < 4; nn++)
#pragma unroll
      for (int j = 0; j < 4; j++) {
        int row = r0 + w * 32 + m * 16 + g * 4 + j;
        if (row < n) {
          int cj = nn * 16 + sr;
          u16* qrow = qweb16 + ((size_t)row << 8) + c0;
          qrow[cj] = f2bf(acc[m][nn][j] + bf[cj]);
          qrow[cj + 64] = f2bf(acc[m][nn + 4][j] + bf[cj + 64]);
        }
      }
}

// ---------- bd-GEMM (K=256) + skip-GEMM (K=128) + finalize + LN2 ----------
__global__ __launch_bounds__(256) void gemm_bd_fin(
    const u16* __restrict__ Aw, const u16* __restrict__ BtW,
    const u16* __restrict__ Ah, const u16* __restrict__ BtS, int n,
    const float* __restrict__ x, const u32* __restrict__ msgb,
    const float* __restrict__ be, const float* __restrict__ bskip,
    const float* __restrict__ lnw, const float* __restrict__ lnb,
    u16* __restrict__ x1b, u16* __restrict__ h2) {
  __shared__ u16 As[2][128 * 32];
  __shared__ u16 Bs[2][128 * 32];
  int t = threadIdx.x;
  int w = t >> 6, lane = t & 63;
  int g = lane >> 4, sr = lane & 15;
  int r0 = blockIdx.x * 128;
  int c0 = 0;
  f32x4 acc[2][8];
#pragma unroll
  for (int m = 0; m < 2; m++)
#pragma unroll
    for (int nn = 0; nn < 8; nn++) acc[m][nn] = {0.f, 0.f, 0.f, 0.f};

  {
    const u16* A = Aw;
    const u16* Bt = BtW;
    constexpr int K = 256;
    GEMM_CORE
  }
  {
    const u16* A = Ah;
    const u16* Bt = BtS;
    constexpr int K = 128;
    GEMM_CORE
  }

  float becol[8], wcol[8], bcol[8], bscol[8];
#pragma unroll
  for (int nn = 0; nn < 8; nn++) {
    int c = nn * 16 + sr;
    becol[nn] = be[c];
    bscol[nn] = bskip[c];
    wcol[nn] = lnw[c];
    bcol[nn] = lnb[c];
  }
#pragma unroll
  for (int m = 0; m < 2; m++)
#pragma unroll
    for (int j = 0; j < 4; j++) {
      int row = r0 + w * 32 + m * 16 + g * 4 + j;
      if (row < n) {
        const float* xr = x + (size_t)row * HID;
        const u32* mr = msgb + ((size_t)row << 6);
        u16* x1r = x1b + (size_t)row * HID;
        u32 mw[4];
#pragma unroll
        for (int nn = 0; nn < 4; nn++) mw[nn] = mr[nn * 16 + sr];
        float tv[8];
        float s = 0.f, s2 = 0.f;
#pragma unroll
        for (int nn = 0; nn < 8; nn++) {
          int c = nn * 16 + sr;
          float mval = nn < 4 ? bflo(mw[nn]) : bfhi(mw[nn - 4]);
          float t1 = xr[c] + mval + acc[m][nn][j] + becol[nn] + bscol[nn];
          tv[nn] = t1;
          s += t1;
          s2 = fmaf(t1, t1, s2);
        }
        s = grp16_sum(s);
        s2 = grp16_sum(s2);
        float mean = s * (1.f / 128.f);
        float var = s2 * (1.f / 128.f) - mean * mean;
        float rs = rsqrtf(var + 1e-5f);
        u16* h2r = h2 + (size_t)row * HID;
#pragma unroll
        for (int nn = 0; nn < 8; nn++) {
          int c = nn * 16 + sr;
          x1r[c] = f2bf(tv[nn]);
          h2r[c] = f2bf((tv[nn] - mean) * rs * wcol[nn] + bcol[nn]);
        }
      }
    }
}

// ---------- fused FFN: GELU(h2@W1+b1)@W2 + b2 + x1 -> out ----------
#define FSTAGE(buf, kc)                                                        \
  {                                                                            \
    {                                                                          \
      int row = t >> 2, c4 = t & 3;                                            \
      __builtin_amdgcn_global_load_lds(                                        \
          (const AS1 u32*)(h2 + (size_t)(r0 + row) * 128 + (kc) + c4 * 8),     \
          (AS3 u32*)&As[buf][t * 8], 16, 0, 0);                                \
    }                                                                          \
    _Pragma("unroll") for (int i = 0; i < 2; i++) {                            \
      int idx = i * 256 + t;                                                   \
      int row = idx >> 2, c4 = idx & 3;                                        \
      __builtin_amdgcn_global_load_lds(                                        \
          (const AS1 u32*)(W1T + (size_t)(c * 128 + row) * 128 + (kc) + c4 * 8), \
          (AS3 u32*)&Bs[buf][idx * 8], 16, 0, 0);                              \
    }                                                                          \
  }

__global__ __launch_bounds__(256) void ffn_fused(
    const u16* __restrict__ h2, const u16* __restrict__ W1T,
    const u16* __restrict__ W2T, const float* __restrict__ b1,
    const float* __restrict__ b2, const u16* __restrict__ x1b,
    float* __restrict__ out, int n) {
  __shared__ u16 As[2][64 * 32];
  __shared__ u16 Bs[2][128 * 32];
  __shared__ u16 T[64 * 136];
  __shared__ u16 Ws2[128 * 132];
  int t = threadIdx.x;
  int w = t >> 6, lane = t & 63;
  int g = lane >> 4, sr = lane & 15;
  int r0 = blockIdx.x * 64;
  f32x4 accO[8];
#pragma unroll
  for (int nn = 0; nn < 8; nn++) accO[nn] = {0.f, 0.f, 0.f, 0.f};

  for (int c = 0; c < 4; c++) {
#pragma unroll
    for (int i = 0; i < 8; i++) {
      int idx = i * 256 + t;
      int m = idx >> 4, k8 = idx & 15;
      u32x4 v = *(const u32x4*)(W2T + (size_t)m * 512 + c * 128 + k8 * 8);
      *(u32x4*)&Ws2[m * 132 + k8 * 8] = v;
    }
    f32x4 acc1[8];
#pragma unroll
    for (int nn = 0; nn < 8; nn++) acc1[nn] = {0.f, 0.f, 0.f, 0.f};
    FSTAGE(0, 0)
    __syncthreads();
#pragma unroll
    for (int tt = 0; tt < 4; tt++) {
      if (tt + 1 < 4) FSTAGE((tt + 1) & 1, (tt + 1) * 32)
      bf16x8 a = *(const bf16x8*)&As[tt & 1][(w * 16 + sr) * 32 + g * 8];
#pragma unroll
      for (int nn = 0; nn < 8; nn++) {
        bf16x8 b = *(const bf16x8*)&Bs[tt & 1][(nn * 16 + sr) * 32 + g * 8];
        acc1[nn] = __builtin_amdgcn_mfma_f32_16x16x32_bf16(a, b, acc1[nn], 0, 0, 0);
      }
      __syncthreads();
    }
#pragma unroll
    for (int nn = 0; nn < 8; nn++) {
      float bc = b1[c * 128 + nn * 16 + sr];
#pragma unroll
      for (int j = 0; j < 4; j++) {
        float v = acc1[nn][j] + bc;
        v = 0.5f * v * (1.f + erff(v * 0.70710678118f));
        T[(w * 16 + g * 4 + j) * 136 + nn * 16 + sr] = f2bf(v);
      }
    }
    __syncthreads();
#pragma unroll
    for (int tt = 0; tt < 4; tt++) {
      bf16x8 a = *(const bf16x8*)&T[(w * 16 + sr) * 136 + tt * 32 + g * 8];
#pragma unroll
      for (int nn = 0; nn < 8; nn++) {
        bf16x8 b = *(const bf16x8*)&Ws2[(nn * 16 + sr) * 132 + tt * 32 + g * 8];
        accO[nn] = __builtin_amdgcn_mfma_f32_16x16x32_bf16(a, b, accO[nn], 0, 0, 0);
      }
    }
    __syncthreads();
  }
#pragma unroll
  for (int nn = 0; nn < 8; nn++) {
#pragma unroll
    for (int j = 0; j < 4; j++) {
      int r = r0 + w * 16 + g * 4 + j;
      if (r < n) {
        int cj = nn * 16 + sr;
        out[(size_t)r * 128 + cj] =
            accO[nn][j] + b2[cj] + bf2f16(x1b[(size_t)r * 128 + cj]);
      }
    }
  }
}

// ---------- counting sort scans + scatter ----------
__global__ __launch_bounds__(256) void scan_partial(const int* __restrict__ cnt,
                                                    int* __restrict__ bs, int N) {
  __shared__ int sd[256];
  int idx = blockIdx.x * 256 + threadIdx.x;
  sd[threadIdx.x] = (idx < N) ? cnt[idx] : 0;
  __syncthreads();
  for (int s = 128; s > 0; s >>= 1) {
    if (threadIdx.x < s) sd[threadIdx.x] += sd[threadIdx.x + s];
    __syncthreads();
  }
  if (threadIdx.x == 0) bs[blockIdx.x] = sd[0];
}

__global__ __launch_bounds__(256) void scan_final(const int* __restrict__ cnt,
                                                  const int* __restrict__ bs,
                                                  int* __restrict__ offs,
                                                  int* __restrict__ woff, int N,
                                                  int nb) {
  __shared__ int sb[256];
  __shared__ int sd[256];
  int t = threadIdx.x;
  sb[t] = (t < nb && t < (int)blockIdx.x) ? bs[t] : 0;
  __syncthreads();
  for (int s = 128; s > 0; s >>= 1) {
    if (t < s) sb[t] += sb[t + s];
    __syncthreads();
  }
  int base = sb[0];
  int idx = blockIdx.x * 256 + t;
  int v = (idx < N) ? cnt[idx] : 0;
  sd[t] = v;
  __syncthreads();
  for (int s = 1; s < 256; s <<= 1) {
    int add = (t >= s) ? sd[t - s] : 0;
    __syncthreads();
    sd[t] += add;
    __syncthreads();
  }
  if (idx < N) {
    int ex = sd[t] - v + base;
    offs[idx] = ex;
    woff[idx] = ex;
  }
}

__global__ __launch_bounds__(256) void scatter_kernel(const int* __restrict__ ei,
                                                      int* __restrict__ woff,
                                                      int2* __restrict__ sorted,
                                                      int E) {
  int i = blockIdx.x * blockDim.x + threadIdx.x;
  int stride = gridDim.x * blockDim.x;
  for (; i < E; i += stride) {
    int src = ei[i];
    int dst = ei[E + i];
    int pos = atomicAdd(&woff[dst], 1);
    sorted[pos] = make_int2(src, i);
  }
}

// ---------- fused edge attention: dual-node zip (2 independent chains/wave) ----------
#define PAIR_ISSUE4(S, P, base_)                                               \
  {                                                                            \
    _Pragma("unroll") for (int jj = 0; jj < 4; jj++) {                         \
      int sj = min((base_) + jj, sM1##S);                                      \
      int sxx = RL(seRx##S, sj);                                               \
      int syy = RL(seRy##S, sj);                                               \
      kv##S##P[jj] = *(const u32x2*)(pkv + ((size_t)sxx << 7) + (lane << 1));  \
      ea##S##P[jj] = *(const float2*)(eaf + ((size_t)syy << 5) + 2 * sr);      \
    }                                                                          \
  }

#define PAIR_COMP4(S, P, base_)                                                \
  {                                                                            \
    _Pragma("unroll") for (int jj = 0; jj < 4; jj++) {                         \
      u32 kx = kv##S##P[jj].x, ky = kv##S##P[jj].y;                            \
      float ex = ea##S##P[jj].x, ey = ea##S##P[jj].y;                          \
      float k0 = bflo(kx), k1 = bfhi(kx);                                      \
      float v0f = bflo(ky), v1f = bfhi(ky);                                    \
      float p0 = fmaf(q0C##S, k0, fmaf(qw0x##S, ex, qw0y##S * ey));            \
      float p1 = fmaf(q1C##S, k1, fmaf(qw1x##S, ex, qw1y##S * ey));            \
      p0 = grp16_sum(p0) + qb0C##S;                                            \
      p1 = grp16_sum(p1) + qb1C##S;                                            \
      bool val_ = (base_) + jj < segn##S;                                      \
      float w1 = val_ ? __builtin_amdgcn_exp2f(p0) : 0.f;                      \
      float w2 = val_ ? __builtin_amdgcn_exp2f(p1) : 0.f;                      \
      l1##S += w1;                                                             \
      l2##S += w2;                                                             \
      a0##S = fmaf(w1, v0f, a0##S);                                            \
      a1##S = fmaf(w2, v1f, a1##S);                                            \
      wa00##S = fmaf(w1, ex, wa00##S);                                         \
      wa01##S = fmaf(w1, ey, wa01##S);                                         \
      wa10##S = fmaf(w2, ex, wa10##S);                                         \
      wa11##S = fmaf(w2, ey, wa11##S);                                         \
    }                                                                          \
  }

#define EPILOGUE(S, node_, num_)                                               \
  {                                                                            \
    float inv1 = 1.f / (l1##S + 1e-30f), inv2 = 1.f / (l2##S + 1e-30f);        \
    if ((num_) > 0)                                                            \
      msgb[((size_t)(node_) << 6) + lane] = pack2(a0##S * inv1, a1##S * inv2); \
    else                                                                       \
      msgb[((size_t)(node_) << 6) + lane] = pack2(-be0, -be1);                 \
    weab[(size_t)(node_)*128 + g * 16 + sr] = pack2(wa00##S * inv1, wa01##S * inv1); \
    weab[(size_t)(node_)*128 + 64 + g * 16 + sr] = pack2(wa10##S * inv2, wa11##S * inv2); \
  }

#define RUN_PAIR(nodeA_, begA_, numA_, seA_, pqA_, qwA0_, qwA1_, nodeB_, begB_, \
                 numB_, seB_, pqB_, qwB0_, qwB1_, exB_)                        \
  {                                                                            \
    float q0CA = bflo(pqA_) * SC, q1CA = bfhi(pqA_) * SC;                      \
    float qw0xA = bflo(qwA0_), qw0yA = bfhi(qwA0_);                            \
    float qw1xA = bflo(qwA1_), qw1yA = bfhi(qwA1_);                            \
    float qb0CA = grp16_sum(q0CA * be0);                                       \
    float qb1CA = grp16_sum(q1CA * be1);                                       \
    float q0CB = bflo(pqB_) * SC, q1CB = bfhi(pqB_) * SC;                      \
    float qw0xB = bflo(qwB0_), qw0yB = bfhi(qwB0_);                            \
    float qw1xB = bflo(qwB1_), qw1yB = bfhi(qwB1_);                            \
    float qb0CB = grp16_sum(q0CB * be0);                                       \
    float qb1CB = grp16_sum(q1CB * be1);                                       \
    float l1A = 0.f, l2A = 0.f, a0A = 0.f, a1A = 0.f;                          \
    float wa00A = 0.f, wa01A = 0.f, wa10A = 0.f, wa11A = 0.f;                  \
    float l1B = 0.f, l2B = 0.f, a0B = 0.f, a1B = 0.f;                          \
    float wa00B = 0.f, wa01B = 0.f, wa10B = 0.f, wa11B = 0.f;                  \
    int seRxA = (seA_).x, seRyA = (seA_).y;                                    \
    int seRxB = (seB_).x, seRyB = (seB_).y;                                    \
    int cbA = 0, cbB = 0;                                                      \
    u32x2 kvA0[4], kvA1[4], kvB0[4], kvB1[4];                                  \
    float2 eaA0[4], eaA1[4], eaB0[4], eaB1[4];                                 \
    while (cbA < (numA_) || cbB < (numB_)) {                                   \
      int segnA = max(min((numA_)-cbA, 64), 0);                                \
      int segnB = max(min((numB_)-cbB, 64), 0);                                \
      int sM1A = max(segnA - 1, 0);                                            \
      int sM1B = max(segnB - 1, 0);                                            \
      PAIR_ISSUE4(A, 0, 0)                                                     \
      PAIR_ISSUE4(B, 0, 0)                                                     \
      int maxn = max(segnA, segnB);                                            \
      for (int c = 0; c < maxn; c += 8) {                                      \
        PAIR_ISSUE4(A, 1, c + 4)                                               \
        PAIR_ISSUE4(B, 1, c + 4)                                               \
        PAIR_COMP4(A, 0, c)                                                    \
        PAIR_COMP4(B, 0, c)                                                    \
        PAIR_ISSUE4(A, 0, c + 8)                                               \
        PAIR_ISSUE4(B, 0, c + 8)                                               \
        PAIR_COMP4(A, 1, c + 4)                                                \
        PAIR_COMP4(B, 1, c + 4)                                                \
      }                                                                        \
      cbA += 64;                                                               \
      cbB += 64;                                                               \
      if (cbA < (numA_)) {                                                     \
        int rem = (numA_)-cbA;                                                 \
        int2 sx = sorted[min((begA_) + cbA + min(lane, rem - 1), Etot - 1)];   \
        seRxA = sx.x;                                                          \
        seRyA = sx.y;                                                          \
      }                                                                        \
      if (cbB < (numB_)) {                                                     \
        int rem = (numB_)-cbB;                                                 \
        int2 sx = sorted[min((begB_) + cbB + min(lane, rem - 1), Etot - 1)];   \
        seRxB = sx.x;                                                          \
        seRyB = sx.y;                                                          \
      }                                                                        \
    }                                                                          \
    EPILOGUE(A, nodeA_, numA_)                                                 \
    if (exB_) EPILOGUE(B, nodeB_, numB_)                                       \
  }

__global__ __launch_bounds__(256) void fused_edge(
    const int* __restrict__ offs, const int* __restrict__ cnt,
    const int2* __restrict__ sorted, const float* __restrict__ eaf,
    const float* __restrict__ be, const u32* __restrict__ pq,
    const u32* __restrict__ pkv, const u16* __restrict__ qweb16,
    u32* __restrict__ msgb, u32* __restrict__ weab, int Nn, int Etot) {
  int lane = threadIdx.x & 63;
  int w = threadIdx.x >> 6;
  int g = lane >> 4, sr = lane & 15;
  int wid = blockIdx.x * 4 + w;
  int nw = gridDim.x * 4;
  int per = (Nn + nw - 1) / nw;
  int n0 = wid * per;
  int n1 = min(Nn, n0 + per);
  if (n0 >= n1) return;
  int nn = n1 - n0;

  float be0 = be[lane], be1 = be[lane + 64];

  int ml = min(lane, nn - 1);
  int myBeg = offs[n0 + ml];
  int myCnt = cnt[n0 + ml];

  int beg0 = RL(myBeg, 0), num0 = RL(myCnt, 0);
  int beg1 = 0, num1 = 0, beg2 = 0, num2 = 0, beg3 = 0, num3 = 0;
  if (nn > 1) { beg1 = RL(myBeg, 1); num1 = RL(myCnt, 1); }
  if (nn > 2) { beg2 = RL(myBeg, 2); num2 = RL(myCnt, 2); }
  if (nn > 3) { beg3 = RL(myBeg, 3); num3 = RL(myCnt, 3); }

  // upfront cooperative edge-index rows + q-state for all nodes (latency overlap)
  int nd1 = n0 + min(1, nn - 1), nd2 = n0 + min(2, nn - 1), nd3 = n0 + min(3, nn - 1);
  int2 se0 = sorted[min(beg0 + min(lane, max(num0 - 1, 0)), Etot - 1)];
  int2 se1 = sorted[min(beg1 + min(lane, max(num1 - 1, 0)), Etot - 1)];
  int2 se2 = sorted[min(beg2 + min(lane, max(num2 - 1, 0)), Etot - 1)];
  int2 se3 = sorted[min(beg3 + min(lane, max(num3 - 1, 0)), Etot - 1)];
  u32 pq0 = pq[(size_t)n0 * 64 + lane];
  u32 pq1 = pq[(size_t)nd1 * 64 + lane];
  u32 pq2 = pq[(size_t)nd2 * 64 + lane];
  u32 pq3 = pq[(size_t)nd3 * 64 + lane];
  u32 qa0 = *(const u32*)(qweb16 + ((size_t)n0 << 8) + g * 32 + 2 * sr);
  u32 qb0_ = *(const u32*)(qweb16 + ((size_t)n0 << 8) + (4 + g) * 32 + 2 * sr);
  u32 qa1 = *(const u32*)(qweb16 + ((size_t)nd1 << 8) + g * 32 + 2 * sr);
  u32 qb1_ = *(const u32*)(qweb16 + ((size_t)nd1 << 8) + (4 + g) * 32 + 2 * sr);
  u32 qa2 = *(const u32*)(qweb16 + ((size_t)nd2 << 8) + g * 32 + 2 * sr);
  u32 qb2_ = *(const u32*)(qweb16 + ((size_t)nd2 << 8) + (4 + g) * 32 + 2 * sr);
  u32 qa3 = *(const u32*)(qweb16 + ((size_t)nd3 << 8) + g * 32 + 2 * sr);
  u32 qb3_ = *(const u32*)(qweb16 + ((size_t)nd3 << 8) + (4 + g) * 32 + 2 * sr);

  RUN_PAIR(n0, beg0, num0, se0, pq0, qa0, qb0_, n0 + 1, beg1, num1, se1, pq1,
           qa1, qb1_, (nn > 1))
  if (nn > 2) {
    RUN_PAIR(n0 + 2, beg2, num2, se2, pq2, qa2, qb2_, n0 + 3, beg3, num3, se3,
             pq3, qa3, qb3_, (nn > 3))
  }
}

extern "C" void kernel_launch(void* const* d_in, const int* in_sizes, int n_in,
                              void* d_out, int out_size, void* d_ws, size_t ws_size,
                              hipStream_t stream) {
  const float* x = (const float*)d_in[0];
  const int* ei = (const int*)d_in[1];
  const float* ea = (const float*)d_in[2];
  const float* Wq = (const float*)d_in[3];
  const float* bq = (const float*)d_in[4];
  const float* Wk = (const float*)d_in[5];
  const float* bk = (const float*)d_in[6];
  const float* Wv = (const float*)d_in[7];
  const float* bv = (const float*)d_in[8];
  const float* We = (const float*)d_in[9];
  const float* be = (const float*)d_in[10];
  const float* Wskip = (const float*)d_in[11];
  const float* bskip = (const float*)d_in[12];
  const float* ln1w = (const float*)d_in[13];
  const float* ln1b = (const float*)d_in[14];
  const float* W1 = (const float*)d_in[15];
  const float* b1p = (const float*)d_in[16];
  const float* W2 = (const float*)d_in[17];
  const float* b2p = (const float*)d_in[18];
  const float* ln2w = (const float*)d_in[19];
  const float* ln2b = (const float*)d_in[20];

  int N = in_sizes[0] / HID;
  int E = in_sizes[1] / 2;
  size_t nf = (size_t)N * HID;

  float* ws = (float*)d_ws;
  size_t off = 0;
  u16* h_bf = (u16*)(ws + off); off += nf / 2;   // live through bd_fin
  u32* pq = (u32*)(ws + off); off += nf / 2;     // [node][64] packed q; reused as h2
  u32* pkv = (u32*)(ws + off); off += nf;        // [node][64]{kword,vword}
  u16* x1b = (u16*)(ws + off); off += nf / 2;    // [node][128] bf16 x1
  u32* msgb = (u32*)(ws + off); off += nf / 2;   // [node][64] packed msg (normalized)
  u32* weab = (u32*)(ws + off); off += nf;       // [node][128] packed wea (normalized)
  u16* qweb16 = (u16*)(ws + off); off += nf;     // [node][256] bf16 qwe
  int2* sorted = (int2*)(ws + off); off += (size_t)E * 2;  // {src, eid}
  int* cnt = (int*)(ws + off); off += N;
  int* offs = (int*)(ws + off); off += N;
  int* woff = (int*)(ws + off); off += N;
  int* bs = (int*)(ws + off); off += 256;
  u16* WqkvsT = (u16*)(ws + off); off += 32768;
  u16* W1T = (u16*)(ws + off); off += 32768;
  u16* W2T = (u16*)(ws + off); off += 32768;
  u16* WbdT = (u16*)(ws + off); off += 16384;
  u16* WfoldT = (u16*)(ws + off); off += 16384;
  float* bfold = ws + off; off += 256;
  u16* h2o = (u16*)pq;  // h2 output (pq dead after fused_edge)

  hipMemsetAsync(cnt, 0, (size_t)N * sizeof(int), stream);

  prelude_kernel<<<3073, 256, 0, stream>>>(Wq, Wk, Wv, Wskip, W1, W2, We, bq,
                                           WqkvsT, W1T, W2T, WbdT, WfoldT, bfold,
                                           x, h_bf, ln1w, ln1b, N, ei + E, cnt, E);

  dim3 gq((N + 127) / 128, 5);
  gemm_qkv<128><<<gq, 256, 0, stream>>>(h_bf, WqkvsT, WfoldT, N, bq, bk, bv,
                                        bfold, pq, pkv, qweb16);

  int nb = (N + 255) / 256;
  scan_partial<<<nb, 256, 0, stream>>>(cnt, bs, N);
  scan_final<<<nb, 256, 0, stream>>>(cnt, bs, offs, woff, N, nb);
  scatter_kernel<<<1024, 256, 0, stream>>>(ei, woff, sorted, E);

  int fe_blocks = (N + 15) / 16;  // 4 waves/block, 4 nodes/wave (2 pairs)
  fused_edge<<<fe_blocks, 256, 0, stream>>>(offs, cnt, sorted, ea, be, pq, pkv,
                                            qweb16, msgb, weab, N, E);

  // bd-GEMM + skip-GEMM + finalize + LN2 fused
  dim3 ge((N + 127) / 128, 1);
  gemm_bd_fin<<<ge, 256, 0, stream>>>((const u16*)weab, WbdT, h_bf,
                                      WqkvsT + 384 * 128, N, x, msgb, be, bskip,
                                      ln2w, ln2b, x1b, h2o);

  // fused FFN
  ffn_fused<<<(N + 63) / 64, 256, 0, stream>>>(h2o, W1T, W2T, b1p, b2p, x1b,
                                               (float*)d_out, N);
}

// Round 18
// 356.424 us; speedup vs baseline: 1.1372x; 1.1372x over previous
//
#include <hip/hip_runtime.h>
#include <math.h>

#define HID 128
#define EDGE_D 32
#define SC 0.36067376f  // 0.25 * log2(e)
#define AS1 __attribute__((address_space(1)))
#define AS3 __attribute__((address_space(3)))

typedef unsigned short u16;
typedef unsigned int u32;
typedef __bf16 bf16x8 __attribute__((ext_vector_type(8)));
typedef float f32x4 __attribute__((ext_vector_type(4)));
typedef u32 u32x4 __attribute__((ext_vector_type(4)));
typedef u32 u32x2 __attribute__((ext_vector_type(2)));

static __device__ __forceinline__ u16 f2bf(float f) {
  u32 u = __float_as_uint(f);
  u += 0x7fffu + ((u >> 16) & 1u);
  return (u16)(u >> 16);
}
static __device__ __forceinline__ u32 pack2(float a, float b) {
  return (u32)f2bf(a) | ((u32)f2bf(b) << 16);
}
static __device__ __forceinline__ float bflo(u32 w) { return __uint_as_float(w << 16); }
static __device__ __forceinline__ float bfhi(u32 w) { return __uint_as_float(w & 0xffff0000u); }
static __device__ __forceinline__ float bf2f16(u16 b) {
  return __uint_as_float(((u32)b) << 16);
}
// all-lanes sum within each 16-lane row via DPP row rotates (pure VALU)
static __device__ __forceinline__ float grp16_sum(float x) {
  x += __int_as_float(__builtin_amdgcn_mov_dpp(__float_as_int(x), 0x128, 0xf, 0xf, true));
  x += __int_as_float(__builtin_amdgcn_mov_dpp(__float_as_int(x), 0x124, 0xf, 0xf, true));
  x += __int_as_float(__builtin_amdgcn_mov_dpp(__float_as_int(x), 0x122, 0xf, 0xf, true));
  x += __int_as_float(__builtin_amdgcn_mov_dpp(__float_as_int(x), 0x121, 0xf, 0xf, true));
  return x;
}
static __device__ __forceinline__ float wave_allreduce_sum(float v) {
#pragma unroll
  for (int off = 32; off > 0; off >>= 1) v += __shfl_xor(v, off);
  return v;
}

// ---------- prelude: weight conversion + Wfold/bfold (blocks 0..1024),
//            LN1 (blocks 1025..2048), dst histogram (blocks 2049..3072) ----------
__global__ __launch_bounds__(256) void prelude_kernel(
    const float* __restrict__ Wq, const float* __restrict__ Wk,
    const float* __restrict__ Wv, const float* __restrict__ Ws,
    const float* __restrict__ W1, const float* __restrict__ W2,
    const float* __restrict__ We, const float* __restrict__ bq,
    u16* __restrict__ WqkvsT, u16* __restrict__ W1T, u16* __restrict__ W2T,
    u16* __restrict__ WbdT, u16* __restrict__ WfoldT, float* __restrict__ bfold,
    const float* __restrict__ x, u16* __restrict__ hout,
    const float* __restrict__ ln1w, const float* __restrict__ ln1b, int Nn,
    const int* __restrict__ dstp, int* __restrict__ cnt, int E) {
  int bid = blockIdx.x;
  if (bid < 1025) {
    int idx = bid * 256 + threadIdx.x;
    if (idx < 65536) {
      int m = idx >> 7, k = idx & 127;
      const float* Wm = m < 128 ? Wq : m < 256 ? Wk : m < 384 ? Wv : Ws;
      WqkvsT[idx] = f2bf(Wm[k * 128 + (m & 127)]);
    } else if (idx < 131072) {
      int j = idx - 65536;
      int m = j >> 7, k = j & 127;
      W1T[j] = f2bf(W1[k * 512 + m]);
    } else if (idx < 196608) {
      int j = idx - 131072;
      int m = j >> 9, k = j & 511;
      W2T[j] = f2bf(W2[k * 128 + m]);
    } else if (idx < 229376) {
      int j = idx - 196608;  // WbdT [128][256]
      int m = j >> 8, c = j & 255;
      WbdT[j] = ((c >> 5) == (m >> 4)) ? f2bf(We[(c & 31) * 128 + m]) : (u16)0;
    } else if (idx < 262144) {
      int j = idx - 229376;  // WfoldT [256][128]
      int m = j >> 7, k = j & 127;
      int base = (m >> 5) * 16;
      const float* wq = Wq + k * 128 + base;
      const float* we = We + (m & 31) * 128 + base;
      float s = 0.f;
#pragma unroll
      for (int t = 0; t < 16; t++) s = fmaf(wq[t], we[t], s);
      WfoldT[j] = f2bf(s * SC);
    } else if (idx < 262400) {
      int m = idx - 262144;  // bfold [256]
      int base = (m >> 5) * 16;
      const float* we = We + (m & 31) * 128 + base;
      float s = 0.f;
#pragma unroll
      for (int t = 0; t < 16; t++) s = fmaf(bq[base + t], we[t], s);
      bfold[m] = s * SC;
    }
  } else if (bid < 2049) {  // LN1, grid-stride over 1024 blocks
    int b = bid - 1025;
    int lane = threadIdx.x & 63;
    int row0 = b * 4 + (threadIdx.x >> 6);
    for (int row = row0; row < Nn; row += 4096) {
      const float* p = x + (size_t)row * HID;
      float a = p[lane], c = p[lane + 64];
      float s = wave_allreduce_sum(a + c);
      float s2 = wave_allreduce_sum(a * a + c * c);
      float mean = s * (1.f / 128.f);
      float var = s2 * (1.f / 128.f) - mean * mean;
      float rs = rsqrtf(var + 1e-5f);
      u16* o = hout + (size_t)row * HID;
      o[lane] = f2bf((a - mean) * rs * ln1w[lane] + ln1b[lane]);
      o[lane + 64] = f2bf((c - mean) * rs * ln1w[lane + 64] + ln1b[lane + 64]);
    }
  } else {  // histogram, grid-stride over 1024 blocks
    int b = bid - 2049;
    for (int i = b * 256 + threadIdx.x; i < E; i += 262144)
      atomicAdd(&cnt[dstp[i]], 1);
  }
}

// ---------- bf16 MFMA GEMM: tile 128x128, 4 waves, 2-phase double-buffered LDS ----------
#define GSTAGE(buf, kc)                                                        \
  {                                                                            \
    _Pragma("unroll") for (int i = 0; i < 2; i++) {                            \
      int idx = i * 256 + t;                                                   \
      int row = idx >> 2, c4 = idx & 3;                                        \
      __builtin_amdgcn_global_load_lds(                                        \
          (const AS1 u32*)(A + (size_t)(r0 + row) * K + (kc) + c4 * 8),        \
          (AS3 u32*)&As[buf][idx * 8], 16, 0, 0);                              \
      __builtin_amdgcn_global_load_lds(                                        \
          (const AS1 u32*)(Bt + (size_t)(c0 + row) * K + (kc) + c4 * 8),       \
          (AS3 u32*)&Bs[buf][idx * 8], 16, 0, 0);                              \
    }                                                                          \
  }

#define GEMM_CORE                                                              \
  constexpr int NT = K / 32;                                                   \
  GSTAGE(0, 0)                                                                 \
  __syncthreads();                                                             \
  _Pragma("unroll") for (int tt = 0; tt < NT; tt++) {                          \
    if (tt + 1 < NT) GSTAGE((tt + 1) & 1, (tt + 1) * 32)                       \
    bf16x8 a0 = *(const bf16x8*)&As[tt & 1][(w * 32 + sr) * 32 + g * 8];       \
    bf16x8 a1 = *(const bf16x8*)&As[tt & 1][(w * 32 + 16 + sr) * 32 + g * 8];  \
    _Pragma("unroll") for (int nn = 0; nn < 8; nn++) {                         \
      bf16x8 b = *(const bf16x8*)&Bs[tt & 1][(nn * 16 + sr) * 32 + g * 8];     \
      acc[0][nn] = __builtin_amdgcn_mfma_f32_16x16x32_bf16(a0, b, acc[0][nn], 0, 0, 0); \
      acc[1][nn] = __builtin_amdgcn_mfma_f32_16x16x32_bf16(a1, b, acc[1][nn], 0, 0, 0); \
    }                                                                          \
    __syncthreads();                                                           \
  }

// QKV GEMM: y0 -> pq packed ; y1/y2 -> pkv packed ; y3/y4 -> qweb16 (+bfold)
template <int K>
__global__ __launch_bounds__(256) void gemm_qkv(
    const u16* __restrict__ A, const u16* __restrict__ BtQ,
    const u16* __restrict__ BtF, int n,
    const float* __restrict__ bias0, const float* __restrict__ bias1,
    const float* __restrict__ bias2, const float* __restrict__ bfold,
    u32* __restrict__ opq, u32* __restrict__ pkv, u16* __restrict__ qweb16) {
  __shared__ u16 As[2][128 * 32];
  __shared__ u16 Bs[2][128 * 32];
  int t = threadIdx.x;
  int w = t >> 6, lane = t & 63;
  int g = lane >> 4, sr = lane & 15;
  int r0 = blockIdx.x * 128;
  int c0;
  const u16* Bt;
  if (blockIdx.y >= 3) {
    c0 = (blockIdx.y - 3) * 128;
    Bt = BtF;
  } else {
    c0 = blockIdx.y * 128;
    Bt = BtQ;
  }
  f32x4 acc[2][8];
#pragma unroll
  for (int m = 0; m < 2; m++)
#pragma unroll
    for (int nn = 0; nn < 8; nn++) acc[m][nn] = {0.f, 0.f, 0.f, 0.f};

  GEMM_CORE

  if (blockIdx.y == 0) {  // Q packed
#pragma unroll
    for (int m = 0; m < 2; m++)
#pragma unroll
      for (int nn = 0; nn < 4; nn++)
#pragma unroll
        for (int j = 0; j < 4; j++) {
          int row = r0 + w * 32 + m * 16 + g * 4 + j;
          if (row < n) {
            int cj = nn * 16 + sr;
            opq[((size_t)row << 6) + cj] =
                pack2(acc[m][nn][j] + bias0[cj], acc[m][nn + 4][j] + bias0[cj + 64]);
          }
        }
    return;
  }
  if (blockIdx.y < 3) {  // K/V packed
    const float* bp = blockIdx.y == 1 ? bias1 : bias2;
    int which = blockIdx.y - 1;
#pragma unroll
    for (int m = 0; m < 2; m++)
#pragma unroll
      for (int nn = 0; nn < 4; nn++)
#pragma unroll
        for (int j = 0; j < 4; j++) {
          int row = r0 + w * 32 + m * 16 + g * 4 + j;
          if (row < n) {
            int cj = nn * 16 + sr;
            pkv[((size_t)row << 7) + (cj << 1) + which] =
                pack2(acc[m][nn][j] + bp[cj], acc[m][nn + 4][j] + bp[cj + 64]);
          }
        }
    return;
  }
  // y3/y4: qwe panels -> u16 [node][256]
  const float* bf = bfold + c0;
#pragma unroll
  for (int m = 0; m < 2; m++)
#pragma unroll
    for (int nn = 0; nn < 4; nn++)
#pragma unroll
      for (int j = 0; j < 4; j++) {
        int row = r0 + w * 32 + m * 16 + g * 4 + j;
        if (row < n) {
          int cj = nn * 16 + sr;
          u16* qrow = qweb16 + ((size_t)row << 8) + c0;
          qrow[cj] = f2bf(acc[m][nn][j] + bf[cj]);
          qrow[cj + 64] = f2bf(acc[m][nn + 4][j] + bf[cj + 64]);
        }
      }
}

// ---------- bd-GEMM (K=256) + skip-GEMM (K=128) + finalize + LN2 ----------
__global__ __launch_bounds__(256) void gemm_bd_fin(
    const u16* __restrict__ Aw, const u16* __restrict__ BtW,
    const u16* __restrict__ Ah, const u16* __restrict__ BtS, int n,
    const float* __restrict__ x, const u32* __restrict__ msgb,
    const float* __restrict__ be, const float* __restrict__ bskip,
    const float* __restrict__ lnw, const float* __restrict__ lnb,
    u16* __restrict__ x1b, u16* __restrict__ h2) {
  __shared__ u16 As[2][128 * 32];
  __shared__ u16 Bs[2][128 * 32];
  int t = threadIdx.x;
  int w = t >> 6, lane = t & 63;
  int g = lane >> 4, sr = lane & 15;
  int r0 = blockIdx.x * 128;
  int c0 = 0;
  f32x4 acc[2][8];
#pragma unroll
  for (int m = 0; m < 2; m++)
#pragma unroll
    for (int nn = 0; nn < 8; nn++) acc[m][nn] = {0.f, 0.f, 0.f, 0.f};

  {
    const u16* A = Aw;
    const u16* Bt = BtW;
    constexpr int K = 256;
    GEMM_CORE
  }
  {
    const u16* A = Ah;
    const u16* Bt = BtS;
    constexpr int K = 128;
    GEMM_CORE
  }

  float becol[8], wcol[8], bcol[8], bscol[8];
#pragma unroll
  for (int nn = 0; nn < 8; nn++) {
    int c = nn * 16 + sr;
    becol[nn] = be[c];
    bscol[nn] = bskip[c];
    wcol[nn] = lnw[c];
    bcol[nn] = lnb[c];
  }
#pragma unroll
  for (int m = 0; m < 2; m++)
#pragma unroll
    for (int j = 0; j < 4; j++) {
      int row = r0 + w * 32 + m * 16 + g * 4 + j;
      if (row < n) {
        const float* xr = x + (size_t)row * HID;
        const u32* mr = msgb + ((size_t)row << 6);
        u16* x1r = x1b + (size_t)row * HID;
        u32 mw[4];
#pragma unroll
        for (int nn = 0; nn < 4; nn++) mw[nn] = mr[nn * 16 + sr];
        float tv[8];
        float s = 0.f, s2 = 0.f;
#pragma unroll
        for (int nn = 0; nn < 8; nn++) {
          int c = nn * 16 + sr;
          float mval = nn < 4 ? bflo(mw[nn]) : bfhi(mw[nn - 4]);
          float t1 = xr[c] + mval + acc[m][nn][j] + becol[nn] + bscol[nn];
          tv[nn] = t1;
          s += t1;
          s2 = fmaf(t1, t1, s2);
        }
        s = grp16_sum(s);
        s2 = grp16_sum(s2);
        float mean = s * (1.f / 128.f);
        float var = s2 * (1.f / 128.f) - mean * mean;
        float rs = rsqrtf(var + 1e-5f);
        u16* h2r = h2 + (size_t)row * HID;
#pragma unroll
        for (int nn = 0; nn < 8; nn++) {
          int c = nn * 16 + sr;
          x1r[c] = f2bf(tv[nn]);
          h2r[c] = f2bf((tv[nn] - mean) * rs * wcol[nn] + bcol[nn]);
        }
      }
    }
}

// ---------- fused FFN: GELU(h2@W1+b1)@W2 + b2 + x1 -> out ----------
#define FSTAGE(buf, kc)                                                        \
  {                                                                            \
    {                                                                          \
      int row = t >> 2, c4 = t & 3;                                            \
      __builtin_amdgcn_global_load_lds(                                        \
          (const AS1 u32*)(h2 + (size_t)(r0 + row) * 128 + (kc) + c4 * 8),     \
          (AS3 u32*)&As[buf][t * 8], 16, 0, 0);                                \
    }                                                                          \
    _Pragma("unroll") for (int i = 0; i < 2; i++) {                            \
      int idx = i * 256 + t;                                                   \
      int row = idx >> 2, c4 = idx & 3;                                        \
      __builtin_amdgcn_global_load_lds(                                        \
          (const AS1 u32*)(W1T + (size_t)(c * 128 + row) * 128 + (kc) + c4 * 8), \
          (AS3 u32*)&Bs[buf][idx * 8], 16, 0, 0);                              \
    }                                                                          \
  }

__global__ __launch_bounds__(256) void ffn_fused(
    const u16* __restrict__ h2, const u16* __restrict__ W1T,
    const u16* __restrict__ W2T, const float* __restrict__ b1,
    const float* __restrict__ b2, const u16* __restrict__ x1b,
    float* __restrict__ out, int n) {
  __shared__ u16 As[2][64 * 32];
  __shared__ u16 Bs[2][128 * 32];
  __shared__ u16 T[64 * 136];
  __shared__ u16 Ws2[128 * 132];
  int t = threadIdx.x;
  int w = t >> 6, lane = t & 63;
  int g = lane >> 4, sr = lane & 15;
  int r0 = blockIdx.x * 64;
  f32x4 accO[8];
#pragma unroll
  for (int nn = 0; nn < 8; nn++) accO[nn] = {0.f, 0.f, 0.f, 0.f};

  for (int c = 0; c < 4; c++) {
#pragma unroll
    for (int i = 0; i < 8; i++) {
      int idx = i * 256 + t;
      int m = idx >> 4, k8 = idx & 15;
      u32x4 v = *(const u32x4*)(W2T + (size_t)m * 512 + c * 128 + k8 * 8);
      *(u32x4*)&Ws2[m * 132 + k8 * 8] = v;
    }
    f32x4 acc1[8];
#pragma unroll
    for (int nn = 0; nn < 8; nn++) acc1[nn] = {0.f, 0.f, 0.f, 0.f};
    FSTAGE(0, 0)
    __syncthreads();
#pragma unroll
    for (int tt = 0; tt < 4; tt++) {
      if (tt + 1 < 4) FSTAGE((tt + 1) & 1, (tt + 1) * 32)
      bf16x8 a = *(const bf16x8*)&As[tt & 1][(w * 16 + sr) * 32 + g * 8];
#pragma unroll
      for (int nn = 0; nn < 8; nn++) {
        bf16x8 b = *(const bf16x8*)&Bs[tt & 1][(nn * 16 + sr) * 32 + g * 8];
        acc1[nn] = __builtin_amdgcn_mfma_f32_16x16x32_bf16(a, b, acc1[nn], 0, 0, 0);
      }
      __syncthreads();
    }
#pragma unroll
    for (int nn = 0; nn < 8; nn++) {
      float bc = b1[c * 128 + nn * 16 + sr];
#pragma unroll
      for (int j = 0; j < 4; j++) {
        float v = acc1[nn][j] + bc;
        v = 0.5f * v * (1.f + erff(v * 0.70710678118f));
        T[(w * 16 + g * 4 + j) * 136 + nn * 16 + sr] = f2bf(v);
      }
    }
    __syncthreads();
#pragma unroll
    for (int tt = 0; tt < 4; tt++) {
      bf16x8 a = *(const bf16x8*)&T[(w * 16 + sr) * 136 + tt * 32 + g * 8];
#pragma unroll
      for (int nn = 0; nn < 8; nn++) {
        bf16x8 b = *(const bf16x8*)&Ws2[(nn * 16 + sr) * 132 + tt * 32 + g * 8];
        accO[nn] = __builtin_amdgcn_mfma_f32_16x16x32_bf16(a, b, accO[nn], 0, 0, 0);
      }
    }
    __syncthreads();
  }
#pragma unroll
  for (int nn = 0; nn < 8; nn++) {
#pragma unroll
    for (int j = 0; j < 4; j++) {
      int r = r0 + w * 16 + g * 4 + j;
      if (r < n) {
        int cj = nn * 16 + sr;
        out[(size_t)r * 128 + cj] =
            accO[nn][j] + b2[cj] + bf2f16(x1b[(size_t)r * 128 + cj]);
      }
    }
  }
}

// ---------- counting sort scans + scatter ----------
__global__ __launch_bounds__(256) void scan_partial(const int* __restrict__ cnt,
                                                    int* __restrict__ bs, int N) {
  __shared__ int sd[256];
  int idx = blockIdx.x * 256 + threadIdx.x;
  sd[threadIdx.x] = (idx < N) ? cnt[idx] : 0;
  __syncthreads();
  for (int s = 128; s > 0; s >>= 1) {
    if (threadIdx.x < s) sd[threadIdx.x] += sd[threadIdx.x + s];
    __syncthreads();
  }
  if (threadIdx.x == 0) bs[blockIdx.x] = sd[0];
}

__global__ __launch_bounds__(256) void scan_final(const int* __restrict__ cnt,
                                                  const int* __restrict__ bs,
                                                  int* __restrict__ offs,
                                                  int* __restrict__ woff, int N,
                                                  int nb) {
  __shared__ int sb[256];
  __shared__ int sd[256];
  int t = threadIdx.x;
  sb[t] = (t < nb && t < (int)blockIdx.x) ? bs[t] : 0;
  __syncthreads();
  for (int s = 128; s > 0; s >>= 1) {
    if (t < s) sb[t] += sb[t + s];
    __syncthreads();
  }
  int base = sb[0];
  int idx = blockIdx.x * 256 + t;
  int v = (idx < N) ? cnt[idx] : 0;
  sd[t] = v;
  __syncthreads();
  for (int s = 1; s < 256; s <<= 1) {
    int add = (t >= s) ? sd[t - s] : 0;
    __syncthreads();
    sd[t] += add;
    __syncthreads();
  }
  if (idx < N) {
    int ex = sd[t] - v + base;
    offs[idx] = ex;
    woff[idx] = ex;
  }
}

__global__ __launch_bounds__(256) void scatter_kernel(const int* __restrict__ ei,
                                                      int* __restrict__ woff,
                                                      int2* __restrict__ sorted,
                                                      int E) {
  int i = blockIdx.x * blockDim.x + threadIdx.x;
  int stride = gridDim.x * blockDim.x;
  for (; i < E; i += stride) {
    int src = ei[i];
    int dst = ei[E + i];
    int pos = atomicAdd(&woff[dst], 1);
    sorted[pos] = make_int2(src, i);
  }
}

// ---------- fused edge attention (2-deep pipeline, 4 nodes/wave) ----------
#define ISSUE4(P, base_)                                                       \
  {                                                                            \
    _Pragma("unroll") for (int jj = 0; jj < 4; jj++) {                         \
      int sj = min(base_ + jj, segn - 1);                                      \
      int sxx = __builtin_amdgcn_readlane(seRx, sj);                           \
      int syy = __builtin_amdgcn_readlane(seRy, sj);                           \
      P##kv[jj] = *(const u32x2*)(pkv + ((size_t)sxx << 7) + (lane << 1));     \
      P##ea[jj] = *(const float2*)(eaf + ((size_t)syy << 5) + 2 * sr);         \
    }                                                                          \
  }

#define COMP4(P, base_)                                                        \
  {                                                                            \
    _Pragma("unroll") for (int jj = 0; jj < 4; jj++) {                         \
      u32 kx = P##kv[jj].x, ky = P##kv[jj].y;                                  \
      float ex = P##ea[jj].x, ey = P##ea[jj].y;                                \
      float k0 = bflo(kx), k1 = bfhi(kx);                                      \
      float v0f = bflo(ky), v1f = bfhi(ky);                                    \
      float p0 = fmaf(q0C, k0, fmaf(qw0x, ex, qw0y * ey));                     \
      float p1 = fmaf(q1C, k1, fmaf(qw1x, ex, qw1y * ey));                     \
      p0 = grp16_sum(p0) + qb0C;                                               \
      p1 = grp16_sum(p1) + qb1C;                                               \
      bool val_ = (base_ + jj) < segn;                                         \
      float w1 = val_ ? __builtin_amdgcn_exp2f(p0) : 0.f;                      \
      float w2 = val_ ? __builtin_amdgcn_exp2f(p1) : 0.f;                      \
      l1 += w1;                                                                \
      l2 += w2;                                                                \
      a0 = fmaf(w1, v0f, a0);                                                  \
      a1 = fmaf(w2, v1f, a1);                                                  \
      wa00 = fmaf(w1, ex, wa00);                                               \
      wa01 = fmaf(w1, ey, wa01);                                               \
      wa10 = fmaf(w2, ex, wa10);                                               \
      wa11 = fmaf(w2, ey, wa11);                                               \
    }                                                                          \
  }

__global__ __launch_bounds__(256) void fused_edge(
    const int* __restrict__ offs, const int* __restrict__ cnt,
    const int2* __restrict__ sorted, const float* __restrict__ eaf,
    const float* __restrict__ be, const u32* __restrict__ pq,
    const u32* __restrict__ pkv, const u16* __restrict__ qweb16,
    u32* __restrict__ msgb, u32* __restrict__ weab, int Nn, int Etot) {
  int lane = threadIdx.x & 63;
  int w = threadIdx.x >> 6;
  int g = lane >> 4, sr = lane & 15;
  int wid = blockIdx.x * 4 + w;
  int nw = gridDim.x * 4;
  int per = (Nn + nw - 1) / nw;
  int n0 = wid * per;
  int n1 = min(Nn, n0 + per);
  if (n0 >= n1) return;
  int nn = n1 - n0;

  float be0 = be[lane], be1 = be[lane + 64];

  int ml = min(lane, nn - 1);
  int myBeg = offs[n0 + ml];
  int myCnt = cnt[n0 + ml];

  // prefetch node 0 state
  int beg = __builtin_amdgcn_readlane(myBeg, 0);
  int num = __builtin_amdgcn_readlane(myCnt, 0);
  int2 se2 = sorted[min(beg + min(lane, max(num - 1, 0)), Etot - 1)];
  int seCx = se2.x, seCy = se2.y;
  u32 pqC = pq[(size_t)n0 * 64 + lane];
  u32 qwb0C = *(const u32*)(qweb16 + ((size_t)n0 << 8) + g * 32 + 2 * sr);
  u32 qwb1C = *(const u32*)(qweb16 + ((size_t)n0 << 8) + (4 + g) * 32 + 2 * sr);

  for (int ni = 0; ni < nn; ni++) {
    int node = n0 + ni;
    // next-node prefetch (independent of current compute)
    int begX = 0, numX = 0, seXx = 0, seXy = 0;
    u32 pqX = 0, qwb0X = 0, qwb1X = 0;
    if (ni + 1 < nn) {
      begX = __builtin_amdgcn_readlane(myBeg, ni + 1);
      numX = __builtin_amdgcn_readlane(myCnt, ni + 1);
      int2 sx = sorted[min(begX + min(lane, max(numX - 1, 0)), Etot - 1)];
      seXx = sx.x;
      seXy = sx.y;
      pqX = pq[(size_t)(node + 1) * 64 + lane];
      qwb0X = *(const u32*)(qweb16 + ((size_t)(node + 1) << 8) + g * 32 + 2 * sr);
      qwb1X = *(const u32*)(qweb16 + ((size_t)(node + 1) << 8) + (4 + g) * 32 + 2 * sr);
    }
    float q0C = bflo(pqC) * SC, q1C = bfhi(pqC) * SC;
    float qw0x = bflo(qwb0C), qw0y = bfhi(qwb0C);
    float qw1x = bflo(qwb1C), qw1y = bfhi(qwb1C);
    // qbe computed in-register: SC * sum_{d in head} q_d * be_d
    float qb0C = grp16_sum(q0C * be0);
    float qb1C = grp16_sum(q1C * be1);
    float l1 = 0.f, l2 = 0.f, a0 = 0.f, a1 = 0.f;
    float wa00 = 0.f, wa01 = 0.f, wa10 = 0.f, wa11 = 0.f;
    if (num > 0) {
      int cb = 0;
      int seRx = seCx, seRy = seCy;
      while (true) {
        int segn = min(num - cb, 64);
        u32x2 Akv[4], Bkv[4];
        float2 Aea[4], Bea[4];
        ISSUE4(A, 0)
        for (int c = 0; c < segn; c += 8) {
          ISSUE4(B, c + 4)
          COMP4(A, c)
          ISSUE4(A, c + 8)
          COMP4(B, c + 4)
        }
        cb += 64;
        if (cb >= num) break;
        int rem = num - cb;
        int2 sn = sorted[min(beg + cb + min(lane, rem - 1), Etot - 1)];
        seRx = sn.x;
        seRy = sn.y;
      }
    }
    // epilogue: normalized packed outputs
    float inv1 = 1.f / (l1 + 1e-30f), inv2 = 1.f / (l2 + 1e-30f);
    if (num > 0) {
      msgb[((size_t)node << 6) + lane] = pack2(a0 * inv1, a1 * inv2);
    } else {  // empty segment: bd_fin adds be -> cancel it
      msgb[((size_t)node << 6) + lane] = pack2(-be0, -be1);
    }
    weab[(size_t)node * 128 + g * 16 + sr] = pack2(wa00 * inv1, wa01 * inv1);
    weab[(size_t)node * 128 + 64 + g * 16 + sr] = pack2(wa10 * inv2, wa11 * inv2);
    beg = begX;
    num = numX;
    seCx = seXx;
    seCy = seXy;
    pqC = pqX;
    qwb0C = qwb0X;
    qwb1C = qwb1X;
  }
}

extern "C" void kernel_launch(void* const* d_in, const int* in_sizes, int n_in,
                              void* d_out, int out_size, void* d_ws, size_t ws_size,
                              hipStream_t stream) {
  const float* x = (const float*)d_in[0];
  const int* ei = (const int*)d_in[1];
  const float* ea = (const float*)d_in[2];
  const float* Wq = (const float*)d_in[3];
  const float* bq = (const float*)d_in[4];
  const float* Wk = (const float*)d_in[5];
  const float* bk = (const float*)d_in[6];
  const float* Wv = (const float*)d_in[7];
  const float* bv = (const float*)d_in[8];
  const float* We = (const float*)d_in[9];
  const float* be = (const float*)d_in[10];
  const float* Wskip = (const float*)d_in[11];
  const float* bskip = (const float*)d_in[12];
  const float* ln1w = (const float*)d_in[13];
  const float* ln1b = (const float*)d_in[14];
  const float* W1 = (const float*)d_in[15];
  const float* b1p = (const float*)d_in[16];
  const float* W2 = (const float*)d_in[17];
  const float* b2p = (const float*)d_in[18];
  const float* ln2w = (const float*)d_in[19];
  const float* ln2b = (const float*)d_in[20];

  int N = in_sizes[0] / HID;
  int E = in_sizes[1] / 2;
  size_t nf = (size_t)N * HID;

  float* ws = (float*)d_ws;
  size_t off = 0;
  u16* h_bf = (u16*)(ws + off); off += nf / 2;   // live through bd_fin
  u32* pq = (u32*)(ws + off); off += nf / 2;     // [node][64] packed q; reused as h2
  u32* pkv = (u32*)(ws + off); off += nf;        // [node][64]{kword,vword}
  u16* x1b = (u16*)(ws + off); off += nf / 2;    // [node][128] bf16 x1
  u32* msgb = (u32*)(ws + off); off += nf / 2;   // [node][64] packed msg (normalized)
  u32* weab = (u32*)(ws + off); off += nf;       // [node][128] packed wea (normalized)
  u16* qweb16 = (u16*)(ws + off); off += nf;     // [node][256] bf16 qwe
  int2* sorted = (int2*)(ws + off); off += (size_t)E * 2;  // {src, eid}
  int* cnt = (int*)(ws + off); off += N;
  int* offs = (int*)(ws + off); off += N;
  int* woff = (int*)(ws + off); off += N;
  int* bs = (int*)(ws + off); off += 256;
  u16* WqkvsT = (u16*)(ws + off); off += 32768;
  u16* W1T = (u16*)(ws + off); off += 32768;
  u16* W2T = (u16*)(ws + off); off += 32768;
  u16* WbdT = (u16*)(ws + off); off += 16384;
  u16* WfoldT = (u16*)(ws + off); off += 16384;
  float* bfold = ws + off; off += 256;
  u16* h2o = (u16*)pq;  // h2 output (pq dead after fused_edge)

  hipMemsetAsync(cnt, 0, (size_t)N * sizeof(int), stream);

  prelude_kernel<<<3073, 256, 0, stream>>>(Wq, Wk, Wv, Wskip, W1, W2, We, bq,
                                           WqkvsT, W1T, W2T, WbdT, WfoldT, bfold,
                                           x, h_bf, ln1w, ln1b, N, ei + E, cnt, E);

  dim3 gq((N + 127) / 128, 5);
  gemm_qkv<128><<<gq, 256, 0, stream>>>(h_bf, WqkvsT, WfoldT, N, bq, bk, bv,
                                        bfold, pq, pkv, qweb16);

  int nb = (N + 255) / 256;
  scan_partial<<<nb, 256, 0, stream>>>(cnt, bs, N);
  scan_final<<<nb, 256, 0, stream>>>(cnt, bs, offs, woff, N, nb);
  scatter_kernel<<<2048, 256, 0, stream>>>(ei, woff, sorted, E);

  int fe_blocks = (N + 15) / 16;  // 4 waves/block, 4 nodes/wave
  fused_edge<<<fe_blocks, 256, 0, stream>>>(offs, cnt, sorted, ea, be, pq, pkv,
                                            qweb16, msgb, weab, N, E);

  // bd-GEMM + skip-GEMM + finalize + LN2 fused
  dim3 ge((N + 127) / 128, 1);
  gemm_bd_fin<<<ge, 256, 0, stream>>>((const u16*)weab, WbdT, h_bf,
                                      WqkvsT + 384 * 128, N, x, msgb, be, bskip,
                                      ln2w, ln2b, x1b, h2o);

  // fused FFN
  ffn_fused<<<(N + 63) / 64, 256, 0, stream>>>(h2o, W1T, W2T, b1p, b2p, x1b,
                                               (float*)d_out, N);
}